// Round 11
// baseline (853.780 us; speedup 1.0000x reference)
//
#include <hip/hip_runtime.h>
#include <cstdint>
#include <cstddef>

#define HID   1024
#define G4    4096
#define BB    64
#define TSEQ  128
#define NSTEP 127
#define AGT   __HIP_MEMORY_SCOPE_AGENT

typedef __attribute__((ext_vector_type(4))) float f32x4;
typedef __attribute__((ext_vector_type(8))) short bf16x8;

__device__ __forceinline__ unsigned short f2bf(float x) {
  union { float f; unsigned u; } v; v.f = x;
  unsigned r = v.u + 0x7FFF + ((v.u >> 16) & 1);   // RNE
  return (unsigned short)(r >> 16);
}
__device__ __forceinline__ float bf2f(unsigned short b) {
  union { unsigned u; float f; } v; v.u = ((unsigned)b) << 16; return v.f;
}
__device__ __forceinline__ float fsigm(float x) { return 1.0f / (1.0f + __expf(-x)); }
__device__ __forceinline__ float ftanh(float x) { return 2.0f / (1.0f + __expf(-2.0f * x)) - 1.0f; }

// ---------------------------------------------------------------------------
__global__ __launch_bounds__(256) void conv_f32_bf16(
    const float* __restrict__ in, unsigned short* __restrict__ out, int n)
{
  int i = (blockIdx.x * 256 + threadIdx.x) * 8;
  if (i >= n) return;
  float4 v0 = *reinterpret_cast<const float4*>(&in[i]);
  float4 v1 = *reinterpret_cast<const float4*>(&in[i + 4]);
  unsigned short u[8];
  u[0] = f2bf(v0.x); u[1] = f2bf(v0.y); u[2] = f2bf(v0.z); u[3] = f2bf(v0.w);
  u[4] = f2bf(v1.x); u[5] = f2bf(v1.y); u[6] = f2bf(v1.z); u[7] = f2bf(v1.w);
  *reinterpret_cast<bf16x8*>(&out[i]) = *reinterpret_cast<bf16x8*>(u);
}

__global__ __launch_bounds__(256) void bias_add(
    const float* __restrict__ b_ih, const float* __restrict__ b_hh,
    float* __restrict__ bias)
{
  int i = blockIdx.x * 256 + threadIdx.x;
  if (i < G4) bias[i] = b_ih[i] + b_hh[i];
}

// ---------------------------------------------------------------------------
// Gather embedding rows for steps [t0, t0+tc) -> bf16 A [Mt][HID].
// ---------------------------------------------------------------------------
__global__ __launch_bounds__(256) void conv_A(
    const int* __restrict__ tgt, const float* __restrict__ emb,
    unsigned short* __restrict__ A, int t0, int tc)
{
  int i = blockIdx.x * 256 + threadIdx.x;
  int m  = i >> 7;
  int k8 = (i & 127) * 8;
  int tl = m >> 6, b = m & 63;
  float4 v0 = make_float4(0.f, 0.f, 0.f, 0.f), v1 = v0;
  if (tl < tc) {
    int tok = tgt[b * TSEQ + t0 + tl];
    if (tok != 0) {
      const float* src = &emb[(size_t)tok * HID + k8];
      v0 = *reinterpret_cast<const float4*>(src);
      v1 = *reinterpret_cast<const float4*>(src + 4);
    }
  }
  unsigned short u[8];
  u[0] = f2bf(v0.x); u[1] = f2bf(v0.y); u[2] = f2bf(v0.z); u[3] = f2bf(v0.w);
  u[4] = f2bf(v1.x); u[5] = f2bf(v1.y); u[6] = f2bf(v1.z); u[7] = f2bf(v1.w);
  *reinterpret_cast<bf16x8*>(&A[(size_t)m * HID + k8]) = *reinterpret_cast<bf16x8*>(u);
}

// ---------------------------------------------------------------------------
// Input GEMM, bf16 MFMA 16x16x32 (verified in R2): gin = A @ w_ih^T + bias.
// ---------------------------------------------------------------------------
__global__ __launch_bounds__(256) void gin_mfma(
    const unsigned short* __restrict__ A, const unsigned short* __restrict__ W,
    const float* __restrict__ bias, float* __restrict__ gin, int Mvalid)
{
  __shared__ unsigned short As[128 * 40];
  __shared__ unsigned short Bs[128 * 40];

  const int tid = threadIdx.x;
  const int m0 = blockIdx.x * 128, n0 = blockIdx.y * 128;
  const int l  = tid & 63, w = tid >> 6;
  const int wr = w >> 1, wc = w & 1;
  const int lr = l & 15, lh = l >> 4;

  f32x4 acc[4][4];
#pragma unroll
  for (int i = 0; i < 4; ++i)
#pragma unroll
    for (int j = 0; j < 4; ++j) acc[i][j] = (f32x4)0.f;

  for (int kc = 0; kc < HID; kc += 32) {
#pragma unroll
    for (int it = 0; it < 2; ++it) {
      int c = tid + it * 256;
      int row = c >> 2, k8 = (c & 3) * 8;
      *reinterpret_cast<bf16x8*>(&As[row * 40 + k8]) =
          *reinterpret_cast<const bf16x8*>(&A[(size_t)(m0 + row) * HID + kc + k8]);
      *reinterpret_cast<bf16x8*>(&Bs[row * 40 + k8]) =
          *reinterpret_cast<const bf16x8*>(&W[(size_t)(n0 + row) * HID + kc + k8]);
    }
    __syncthreads();

    bf16x8 af[4], bfr[4];
#pragma unroll
    for (int i = 0; i < 4; ++i) {
      af[i]  = *reinterpret_cast<const bf16x8*>(&As[(wr * 64 + i * 16 + lr) * 40 + lh * 8]);
      bfr[i] = *reinterpret_cast<const bf16x8*>(&Bs[(wc * 64 + i * 16 + lr) * 40 + lh * 8]);
    }
#pragma unroll
    for (int i = 0; i < 4; ++i)
#pragma unroll
      for (int j = 0; j < 4; ++j)
        acc[i][j] = __builtin_amdgcn_mfma_f32_16x16x32_bf16(af[i], bfr[j], acc[i][j], 0, 0, 0);
    __syncthreads();
  }

#pragma unroll
  for (int j = 0; j < 4; ++j) {
    int n = n0 + wc * 64 + j * 16 + lr;
    float bn = bias[n];
#pragma unroll
    for (int i = 0; i < 4; ++i) {
      int mb = m0 + wr * 64 + i * 16 + lh * 4;
#pragma unroll
      for (int r = 0; r < 4; ++r) {
        int m = mb + r;
        if (m < Mvalid) gin[(size_t)m * G4 + n] = acc[i][j][r] + bn;
      }
    }
  }
}

// ---------------------------------------------------------------------------
// Persistent LSTM — R5's proven engine, store-free loop.
// 256 blocks = 4 batch-groups x 64 unit-blocks. Per step: w_hh fragment
// loads + gin prefetch issued BEFORE the poll (latency hides under the
// producer wait); flag poll (packed 4B flags, 256 B/row); bulk h load from
// hbuf[t] (L3-direct); MFMA; LDS cross-wave reduce; activations (c in reg);
// publish h into hbuf[t+1] (this IS the output record); one drain;  flag.
// NO HBM stores inside the loop. out is expanded from hbuf afterwards.
// ---------------------------------------------------------------------------
__global__ __launch_bounds__(256, 1) void lstm_persist(
    const unsigned short* __restrict__ whh, const float* __restrict__ gin,
    unsigned short* __restrict__ hbuf, float* __restrict__ c_ws,
    const float* __restrict__ c0, unsigned int* __restrict__ flags,
    int t0, int tc)
{
  __shared__ float red[4][4][16][16];   // [wave][gate][batch][unit]

  const int tid = threadIdx.x;
  const int l = tid & 63, w = tid >> 6;
  const int lr = l & 15, lh = l >> 4;
  const int grp = blockIdx.x >> 6;      // batch group [0,4)
  const int ub  = blockIdx.x & 63;      // unit block  [0,64)
  const int b0 = grp * 16;
  const int u0 = ub * 16;

  const int bi = tid >> 4, ui = tid & 15;
  const size_t ci = (size_t)(b0 + bi) * HID + u0 + ui;
  float c_reg = (t0 == 0) ? c0[ci] : c_ws[ci];

  const unsigned long long* hq = reinterpret_cast<const unsigned long long*>(hbuf);
  unsigned int* hw = reinterpret_cast<unsigned int*>(hbuf);
  const size_t SLOT_Q = (size_t)BB * HID / 4;   // 8B words per time slot
  const size_t SLOT_W = (size_t)BB * HID / 2;   // 4B words per time slot
  const size_t hrow_q = ((size_t)(b0 + lr) * HID) >> 2;

  for (int tl = 0; tl < tc; ++tl) {
    const int t = t0 + tl;

    // --- issue w_hh fragment loads early (in flight during the poll) ---
    bf16x8 bw[4][8];
#pragma unroll
    for (int g = 0; g < 4; ++g)
#pragma unroll
      for (int kk = 0; kk < 8; ++kk)
        bw[g][kk] = *reinterpret_cast<const bf16x8*>(
            &whh[(size_t)(g * HID + u0 + lr) * HID + w * 256 + kk * 32 + lh * 8]);

    // --- gin prefetch (independent of h; in flight during the poll) ---
    float gi[4];
#pragma unroll
    for (int g = 0; g < 4; ++g)
      gi[g] = gin[((size_t)tl * BB + b0 + bi) * G4 + g * HID + u0 + ui];

    // --- poll h_t flags: lane l watches producer block l (packed 4B) ---
    if (t > 0) {
      const unsigned int* fl = flags + ((size_t)(t - 1) * 4 + grp) * 64 + l;
      while (true) {
        unsigned v = __hip_atomic_load(fl, __ATOMIC_RELAXED, AGT);
        if (__all(v != 0)) break;
        __builtin_amdgcn_s_sleep(2);
      }
    }

    // --- bulk h load from hbuf[t] (L3-direct) + MFMA ---
    f32x4 acc[4];
#pragma unroll
    for (int g = 0; g < 4; ++g) acc[g] = (f32x4)0.f;
#pragma unroll
    for (int kk = 0; kk < 8; ++kk) {
      size_t base = (size_t)t * SLOT_Q + hrow_q + (size_t)w * 64 + kk * 8 + lh * 2;
      unsigned long long lo = __hip_atomic_load(&hq[base],     __ATOMIC_RELAXED, AGT);
      unsigned long long hi = __hip_atomic_load(&hq[base + 1], __ATOMIC_RELAXED, AGT);
      union { unsigned long long q[2]; bf16x8 v; } u;
      u.q[0] = lo; u.q[1] = hi;
      bf16x8 af = u.v;
#pragma unroll
      for (int g = 0; g < 4; ++g)
        acc[g] = __builtin_amdgcn_mfma_f32_16x16x32_bf16(af, bw[g][kk], acc[g], 0, 0, 0);
    }

    // --- cross-wave K reduce ---
#pragma unroll
    for (int g = 0; g < 4; ++g)
#pragma unroll
      for (int r = 0; r < 4; ++r)
        red[w][g][lh * 4 + r][lr] = acc[g][r];
    __syncthreads();

    float gates[4];
#pragma unroll
    for (int g = 0; g < 4; ++g)
      gates[g] = red[0][g][bi][ui] + red[1][g][bi][ui] +
                 red[2][g][bi][ui] + red[3][g][bi][ui] + gi[g];

    float iv = fsigm(gates[0]);
    float fv = fsigm(gates[1]);
    float gv = ftanh(gates[2]);
    float ov = fsigm(gates[3]);
    c_reg = fv * c_reg + iv * gv;
    float hn = ov * ftanh(c_reg);

    // --- publish h_{t+1} into hbuf[t+1] (L3-direct, 4B packed pairs) ---
    unsigned hv = (unsigned)f2bf(hn);
    unsigned pv = (unsigned)__shfl_xor((int)hv, 1);
    if ((tid & 1) == 0) {
      unsigned word = (hv & 0xffffu) | (pv << 16);
      __hip_atomic_store(&hw[(size_t)(t + 1) * SLOT_W + (ci >> 1)], word,
                         __ATOMIC_RELAXED, AGT);
    }

    // one drain for the L3 publishes (syncthreads waits vmcnt(0)), then flag
    __syncthreads();
    if (tid == 0)
      __hip_atomic_store(&flags[((size_t)t * 4 + grp) * 64 + ub], 1u,
                         __ATOMIC_RELAXED, AGT);
  }
  c_ws[ci] = c_reg;
}

// ---------------------------------------------------------------------------
// Expand hbuf (bf16 h history) -> out fp32: outputs[b][t][u] = hbuf[t+1],
// then h_n = hbuf[NSTEP], c_n = c_ws.
// ---------------------------------------------------------------------------
__global__ __launch_bounds__(256) void out_expand(
    const unsigned short* __restrict__ hbuf, const float* __restrict__ c_ws,
    float* __restrict__ out)
{
  const int MAIN8 = BB * NSTEP * HID / 8;   // 1,040,384
  const int HN8   = BB * HID / 8;           // 8,192
  const int C4    = BB * HID / 4;           // 16,384
  int i = blockIdx.x * 256 + threadIdx.x;

  if (i < MAIN8) {
    int base = i * 8;
    int u0 = base & (HID - 1);
    int bt = base >> 10;            // /HID
    int t = bt % NSTEP, b = bt / NSTEP;
    bf16x8 v = *reinterpret_cast<const bf16x8*>(
        &hbuf[((size_t)(t + 1) * BB + b) * HID + u0]);
    float4 f0, f1;
    f0.x = bf2f(((unsigned short*)&v)[0]); f0.y = bf2f(((unsigned short*)&v)[1]);
    f0.z = bf2f(((unsigned short*)&v)[2]); f0.w = bf2f(((unsigned short*)&v)[3]);
    f1.x = bf2f(((unsigned short*)&v)[4]); f1.y = bf2f(((unsigned short*)&v)[5]);
    f1.z = bf2f(((unsigned short*)&v)[6]); f1.w = bf2f(((unsigned short*)&v)[7]);
    *reinterpret_cast<float4*>(&out[base])     = f0;
    *reinterpret_cast<float4*>(&out[base + 4]) = f1;
    return;
  }
  i -= MAIN8;
  size_t tail = (size_t)BB * NSTEP * HID;
  if (i < HN8) {
    int base = i * 8;
    bf16x8 v = *reinterpret_cast<const bf16x8*>(
        &hbuf[(size_t)NSTEP * BB * HID + base]);
    float4 f0, f1;
    f0.x = bf2f(((unsigned short*)&v)[0]); f0.y = bf2f(((unsigned short*)&v)[1]);
    f0.z = bf2f(((unsigned short*)&v)[2]); f0.w = bf2f(((unsigned short*)&v)[3]);
    f1.x = bf2f(((unsigned short*)&v)[4]); f1.y = bf2f(((unsigned short*)&v)[5]);
    f1.z = bf2f(((unsigned short*)&v)[6]); f1.w = bf2f(((unsigned short*)&v)[7]);
    *reinterpret_cast<float4*>(&out[tail + base])     = f0;
    *reinterpret_cast<float4*>(&out[tail + base + 4]) = f1;
    return;
  }
  i -= HN8;
  if (i < C4) {
    int base = i * 4;
    *reinterpret_cast<float4*>(&out[tail + (size_t)BB * HID + base]) =
        *reinterpret_cast<const float4*>(&c_ws[base]);
  }
}

// ---------------------------------------------------------------------------
extern "C" void kernel_launch(void* const* d_in, const int* in_sizes, int n_in,
                              void* d_out, int out_size, void* d_ws, size_t ws_size,
                              hipStream_t stream)
{
  const int*   tgt  = (const int*)d_in[0];
  const float* h0   = (const float*)d_in[1];
  const float* c0   = (const float*)d_in[2];
  const float* emb  = (const float*)d_in[5];
  const float* w_ih = (const float*)d_in[6];
  const float* w_hh = (const float*)d_in[7];
  const float* b_ih = (const float*)d_in[8];
  const float* b_hh = (const float*)d_in[9];
  float* out = (float*)d_out;

  const size_t FLAGS_BYTES = (size_t)NSTEP * 4 * 64 * 4;           // packed 4B
  const size_t HBUF_BYTES  = (size_t)(NSTEP + 1) * BB * HID * 2;   // bf16 history

  char* p = (char*)d_ws;
  unsigned short* wih_bf = (unsigned short*)p;  p += (size_t)G4 * HID * 2;
  unsigned short* whh_bf = (unsigned short*)p;  p += (size_t)G4 * HID * 2;
  float*          bias   = (float*)p;           p += (size_t)G4 * 4;
  unsigned short* hbuf   = (unsigned short*)p;  p += HBUF_BYTES;
  float*          c_ws   = (float*)p;           p += (size_t)BB * HID * 4;
  unsigned int*   flags  = (unsigned int*)p;    p += FLAGS_BYTES;

  size_t fixed = (size_t)(p - (char*)d_ws);
  size_t rem = (ws_size > fixed) ? ws_size - fixed : 0;
  int Tc = (int)((rem > 262144 ? rem - 262144 : 0) / 1179648);
  if (Tc > NSTEP) Tc = NSTEP;
  if (Tc < 1) return;

  int MtMax = ((Tc * BB + 127) / 128) * 128;
  unsigned short* A_bf = (unsigned short*)p; p += (size_t)MtMax * HID * 2;
  float*          gin  = (float*)p;

  hipMemsetAsync(flags, 0, FLAGS_BYTES, stream);
  conv_f32_bf16<<<dim3((G4 * HID) / 8 / 256), 256, 0, stream>>>(w_ih, wih_bf, G4 * HID);
  conv_f32_bf16<<<dim3((G4 * HID) / 8 / 256), 256, 0, stream>>>(w_hh, whh_bf, G4 * HID);
  bias_add<<<dim3(G4 / 256), 256, 0, stream>>>(b_ih, b_hh, bias);
  // hbuf slot 0 = h0 (bf16)
  conv_f32_bf16<<<dim3((BB * HID) / 8 / 256), 256, 0, stream>>>(h0, hbuf, BB * HID);

  for (int t0 = 0; t0 < NSTEP; t0 += Tc) {
    int tc = (NSTEP - t0 < Tc) ? (NSTEP - t0) : Tc;
    int Mt = ((tc * BB + 127) / 128) * 128;
    conv_A<<<dim3(Mt / 2), 256, 0, stream>>>(tgt, emb, A_bf, t0, tc);
    gin_mfma<<<dim3(Mt / 128, G4 / 128), 256, 0, stream>>>(A_bf, wih_bf, bias, gin, tc * BB);

    void* kargs[] = { (void*)&whh_bf, (void*)&gin, (void*)&hbuf, (void*)&c_ws,
                      (void*)&c0, (void*)&flags, (void*)&t0, (void*)&tc };
    hipLaunchCooperativeKernel((void*)lstm_persist, dim3(256), dim3(256),
                               kargs, 0, stream);
  }

  const int TOT = BB * NSTEP * HID / 8 + BB * HID / 8 + BB * HID / 4;
  out_expand<<<dim3((TOT + 255) / 256), 256, 0, stream>>>(hbuf, c_ws, out);
}

// Round 13
// 748.172 us; speedup vs baseline: 1.1412x; 1.1412x over previous
//
#include <hip/hip_runtime.h>
#include <cstdint>
#include <cstddef>

#define HID   1024
#define G4    4096
#define BB    64
#define TSEQ  128
#define NSTEP 127
#define AGT   __HIP_MEMORY_SCOPE_AGENT

typedef __attribute__((ext_vector_type(4))) float f32x4;
typedef __attribute__((ext_vector_type(8))) short bf16x8;

__device__ __forceinline__ unsigned short f2bf(float x) {
  union { float f; unsigned u; } v; v.f = x;
  unsigned r = v.u + 0x7FFF + ((v.u >> 16) & 1);   // RNE
  return (unsigned short)(r >> 16);
}
__device__ __forceinline__ float bf2f(unsigned short b) {
  union { unsigned u; float f; } v; v.u = ((unsigned)b) << 16; return v.f;
}
__device__ __forceinline__ float fsigm(float x) { return 1.0f / (1.0f + __expf(-x)); }
__device__ __forceinline__ float ftanh(float x) { return 2.0f / (1.0f + __expf(-2.0f * x)) - 1.0f; }

// ---------------------------------------------------------------------------
__global__ __launch_bounds__(256) void conv_f32_bf16(
    const float* __restrict__ in, unsigned short* __restrict__ out, int n)
{
  int i = (blockIdx.x * 256 + threadIdx.x) * 8;
  if (i >= n) return;
  float4 v0 = *reinterpret_cast<const float4*>(&in[i]);
  float4 v1 = *reinterpret_cast<const float4*>(&in[i + 4]);
  unsigned short u[8];
  u[0] = f2bf(v0.x); u[1] = f2bf(v0.y); u[2] = f2bf(v0.z); u[3] = f2bf(v0.w);
  u[4] = f2bf(v1.x); u[5] = f2bf(v1.y); u[6] = f2bf(v1.z); u[7] = f2bf(v1.w);
  *reinterpret_cast<bf16x8*>(&out[i]) = *reinterpret_cast<bf16x8*>(u);
}

__global__ __launch_bounds__(256) void bias_add(
    const float* __restrict__ b_ih, const float* __restrict__ b_hh,
    float* __restrict__ bias)
{
  int i = blockIdx.x * 256 + threadIdx.x;
  if (i < G4) bias[i] = b_ih[i] + b_hh[i];
}

// ---------------------------------------------------------------------------
// Gather embedding rows for steps [t0, t0+tc) -> bf16 A [Mt][HID].
// ---------------------------------------------------------------------------
__global__ __launch_bounds__(256) void conv_A(
    const int* __restrict__ tgt, const float* __restrict__ emb,
    unsigned short* __restrict__ A, int t0, int tc)
{
  int i = blockIdx.x * 256 + threadIdx.x;
  int m  = i >> 7;
  int k8 = (i & 127) * 8;
  int tl = m >> 6, b = m & 63;
  float4 v0 = make_float4(0.f, 0.f, 0.f, 0.f), v1 = v0;
  if (tl < tc) {
    int tok = tgt[b * TSEQ + t0 + tl];
    if (tok != 0) {
      const float* src = &emb[(size_t)tok * HID + k8];
      v0 = *reinterpret_cast<const float4*>(src);
      v1 = *reinterpret_cast<const float4*>(src + 4);
    }
  }
  unsigned short u[8];
  u[0] = f2bf(v0.x); u[1] = f2bf(v0.y); u[2] = f2bf(v0.z); u[3] = f2bf(v0.w);
  u[4] = f2bf(v1.x); u[5] = f2bf(v1.y); u[6] = f2bf(v1.z); u[7] = f2bf(v1.w);
  *reinterpret_cast<bf16x8*>(&A[(size_t)m * HID + k8]) = *reinterpret_cast<bf16x8*>(u);
}

// ---------------------------------------------------------------------------
// Input GEMM, bf16 MFMA 16x16x32 (verified in R2): gin = A @ w_ih^T + bias.
// ---------------------------------------------------------------------------
__global__ __launch_bounds__(256) void gin_mfma(
    const unsigned short* __restrict__ A, const unsigned short* __restrict__ W,
    const float* __restrict__ bias, float* __restrict__ gin, int Mvalid)
{
  __shared__ unsigned short As[128 * 40];
  __shared__ unsigned short Bs[128 * 40];

  const int tid = threadIdx.x;
  const int m0 = blockIdx.x * 128, n0 = blockIdx.y * 128;
  const int l  = tid & 63, w = tid >> 6;
  const int wr = w >> 1, wc = w & 1;
  const int lr = l & 15, lh = l >> 4;

  f32x4 acc[4][4];
#pragma unroll
  for (int i = 0; i < 4; ++i)
#pragma unroll
    for (int j = 0; j < 4; ++j) acc[i][j] = (f32x4)0.f;

  for (int kc = 0; kc < HID; kc += 32) {
#pragma unroll
    for (int it = 0; it < 2; ++it) {
      int c = tid + it * 256;
      int row = c >> 2, k8 = (c & 3) * 8;
      *reinterpret_cast<bf16x8*>(&As[row * 40 + k8]) =
          *reinterpret_cast<const bf16x8*>(&A[(size_t)(m0 + row) * HID + kc + k8]);
      *reinterpret_cast<bf16x8*>(&Bs[row * 40 + k8]) =
          *reinterpret_cast<const bf16x8*>(&W[(size_t)(n0 + row) * HID + kc + k8]);
    }
    __syncthreads();

    bf16x8 af[4], bfr[4];
#pragma unroll
    for (int i = 0; i < 4; ++i) {
      af[i]  = *reinterpret_cast<const bf16x8*>(&As[(wr * 64 + i * 16 + lr) * 40 + lh * 8]);
      bfr[i] = *reinterpret_cast<const bf16x8*>(&Bs[(wc * 64 + i * 16 + lr) * 40 + lh * 8]);
    }
#pragma unroll
    for (int i = 0; i < 4; ++i)
#pragma unroll
      for (int j = 0; j < 4; ++j)
        acc[i][j] = __builtin_amdgcn_mfma_f32_16x16x32_bf16(af[i], bfr[j], acc[i][j], 0, 0, 0);
    __syncthreads();
  }

#pragma unroll
  for (int j = 0; j < 4; ++j) {
    int n = n0 + wc * 64 + j * 16 + lr;
    float bn = bias[n];
#pragma unroll
    for (int i = 0; i < 4; ++i) {
      int mb = m0 + wr * 64 + i * 16 + lh * 4;
#pragma unroll
      for (int r = 0; r < 4; ++r) {
        int m = mb + r;
        if (m < Mvalid) gin[(size_t)m * G4 + n] = acc[i][j][r] + bn;
      }
    }
  }
}

// ---------------------------------------------------------------------------
// Persistent LSTM — R5 engine + LDS-resident w_hh + bf16 history store.
// 256 blocks = 4 batch-groups x 64 unit-blocks; groups XCD-aligned via
// blockIdx&7 (perf heuristic only). Per step:
//   gin prefetch (pre-poll, hides under producer wait)
//   flag poll (16B-stride flags, 64 lanes x 4B per probe)
//   bulk h load (L3-direct) + MFMA with w_hh from LDS (no global deps)
//   LDS cross-wave reduce, activations (c in register)
//   publish packed bf16 word to hot double-buffer + history slot (pre-flag)
//   one vmcnt drain (inside syncthreads), single flag store
// NO HBM-bound stores in the loop; out expanded from history afterwards.
// ---------------------------------------------------------------------------
__global__ __launch_bounds__(256, 1) void lstm_persist(
    const unsigned short* __restrict__ whh, const float* __restrict__ gin,
    unsigned int* __restrict__ hb0, unsigned int* __restrict__ hb1,
    unsigned int* __restrict__ hhist, float* __restrict__ c_ws,
    const float* __restrict__ c0, unsigned int* __restrict__ flags,
    int t0, int tc)
{
  __shared__ unsigned short wh_lds[4 * 4 * 8 * 512];   // [w][g][kk][l*8] = 128 KB
  __shared__ float red[4][4][16][16];                   // 16 KB

  const int tid = threadIdx.x;
  const int l = tid & 63, w = tid >> 6;
  const int lr = l & 15, lh = l >> 4;
  const int xcd = blockIdx.x & 7;
  const int grp = xcd >> 1;                       // group g on XCDs {2g,2g+1}
  const int ub  = ((blockIdx.x >> 3) << 1) | (xcd & 1);
  const int b0 = grp * 16;
  const int u0 = ub * 16;

  // --- stage w_hh slice into LDS once (same fragment layout as R5's bw) ---
  for (int idx = tid; idx < 8192; idx += 256) {
    int ll = idx & 63, kk = (idx >> 6) & 7, g = (idx >> 9) & 3, ww = (idx >> 11) & 3;
    bf16x8 v = *reinterpret_cast<const bf16x8*>(
        &whh[(size_t)(g * HID + u0 + (ll & 15)) * HID + ww * 256 + kk * 32 + (ll >> 4) * 8]);
    *reinterpret_cast<bf16x8*>(&wh_lds[(size_t)idx * 8]) = v;
  }

  const int bi = tid >> 4, ui = tid & 15;
  const size_t ci = (size_t)(b0 + bi) * HID + u0 + ui;
  float c_reg = (t0 == 0) ? c0[ci] : c_ws[ci];

  __syncthreads();   // LDS staged

  const size_t hbase  = ((size_t)(b0 + lr) * HID) >> 1;   // 4B-word base of batch row
  const size_t SLOT_W = (size_t)BB * HID / 2;             // 4B words per time slot

  for (int tl = 0; tl < tc; ++tl) {
    const int t = t0 + tl;
    const unsigned int* hin  = (t & 1) ? hb1 : hb0;
    unsigned int*       hout = (t & 1) ? hb0 : hb1;

    // --- gin prefetch (independent of h; in flight during the poll) ---
    float gi[4];
#pragma unroll
    for (int g = 0; g < 4; ++g)
      gi[g] = gin[((size_t)tl * BB + b0 + bi) * G4 + g * HID + u0 + ui];

    // --- poll h_t flags: lane l watches producer block l (16B stride) ---
    if (t > 0) {
      const unsigned int* fl = flags + (((size_t)(t - 1) * 4 + grp) * 64 + l) * 4;
      while (true) {
        unsigned v = __hip_atomic_load(fl, __ATOMIC_RELAXED, AGT);
        if (__all(v != 0)) break;
        __builtin_amdgcn_s_sleep(2);
      }
    }

    // --- bulk h load (L3-direct) + MFMA with LDS-resident w_hh ---
    f32x4 acc[4];
#pragma unroll
    for (int g = 0; g < 4; ++g) acc[g] = (f32x4)0.f;
#pragma unroll
    for (int kk = 0; kk < 8; ++kk) {
      size_t base = hbase + (size_t)w * 128 + kk * 16 + lh * 4;
      unsigned long long lo = __hip_atomic_load(
          reinterpret_cast<const unsigned long long*>(&hin[base]), __ATOMIC_RELAXED, AGT);
      unsigned long long hi = __hip_atomic_load(
          reinterpret_cast<const unsigned long long*>(&hin[base + 2]), __ATOMIC_RELAXED, AGT);
      union { unsigned long long q[2]; bf16x8 v; } u;
      u.q[0] = lo; u.q[1] = hi;
      bf16x8 af = u.v;
#pragma unroll
      for (int g = 0; g < 4; ++g) {
        bf16x8 bw = *reinterpret_cast<const bf16x8*>(
            &wh_lds[(size_t)(((w * 4 + g) * 8 + kk) * 512 + l * 8)]);
        acc[g] = __builtin_amdgcn_mfma_f32_16x16x32_bf16(af, bw, acc[g], 0, 0, 0);
      }
    }

    // --- cross-wave K reduce ---
#pragma unroll
    for (int g = 0; g < 4; ++g)
#pragma unroll
      for (int r = 0; r < 4; ++r)
        red[w][g][lh * 4 + r][lr] = acc[g][r];
    __syncthreads();

    float gates[4];
#pragma unroll
    for (int g = 0; g < 4; ++g)
      gates[g] = red[0][g][bi][ui] + red[1][g][bi][ui] +
                 red[2][g][bi][ui] + red[3][g][bi][ui] + gi[g];

    float iv = fsigm(gates[0]);
    float fv = fsigm(gates[1]);
    float gv = ftanh(gates[2]);
    float ov = fsigm(gates[3]);
    c_reg = fv * c_reg + iv * gv;
    float hn = ov * ftanh(c_reg);

    // --- publish h_{t+1} (hot dbuf, L3-direct) + bf16 history (pre-flag) ---
    unsigned hv = (unsigned)f2bf(hn);
    unsigned pv = (unsigned)__shfl_xor((int)hv, 1);
    if ((tid & 1) == 0) {
      unsigned word = (hv & 0xffffu) | (pv << 16);
      __hip_atomic_store(&hout[ci >> 1], word, __ATOMIC_RELAXED, AGT);
      hhist[(size_t)(t + 1) * SLOT_W + (ci >> 1)] = word;   // plain store (L2 ack)
    }

    // one drain for all in-loop stores, then the single flag store
    asm volatile("s_waitcnt vmcnt(0)");
    __syncthreads();
    if (tid == 0)
      __hip_atomic_store(&flags[(((size_t)t * 4 + grp) * 64 + ub) * 4], 1u,
                         __ATOMIC_RELAXED, AGT);
  }
  c_ws[ci] = c_reg;
}

// ---------------------------------------------------------------------------
// Expand hhist (bf16 h history) -> out fp32; h_n = hhist[NSTEP]; c_n = c_ws.
// ---------------------------------------------------------------------------
__global__ __launch_bounds__(256) void out_expand(
    const unsigned short* __restrict__ hbuf, const float* __restrict__ c_ws,
    float* __restrict__ out)
{
  const int MAIN8 = BB * NSTEP * HID / 8;
  const int HN8   = BB * HID / 8;
  const int C4    = BB * HID / 4;
  int i = blockIdx.x * 256 + threadIdx.x;

  if (i < MAIN8) {
    int base = i * 8;
    int u0 = base & (HID - 1);
    int bt = base >> 10;
    int t = bt % NSTEP, b = bt / NSTEP;
    bf16x8 v = *reinterpret_cast<const bf16x8*>(
        &hbuf[((size_t)(t + 1) * BB + b) * HID + u0]);
    float4 f0, f1;
    f0.x = bf2f(((unsigned short*)&v)[0]); f0.y = bf2f(((unsigned short*)&v)[1]);
    f0.z = bf2f(((unsigned short*)&v)[2]); f0.w = bf2f(((unsigned short*)&v)[3]);
    f1.x = bf2f(((unsigned short*)&v)[4]); f1.y = bf2f(((unsigned short*)&v)[5]);
    f1.z = bf2f(((unsigned short*)&v)[6]); f1.w = bf2f(((unsigned short*)&v)[7]);
    *reinterpret_cast<float4*>(&out[base])     = f0;
    *reinterpret_cast<float4*>(&out[base + 4]) = f1;
    return;
  }
  i -= MAIN8;
  size_t tail = (size_t)BB * NSTEP * HID;
  if (i < HN8) {
    int base = i * 8;
    bf16x8 v = *reinterpret_cast<const bf16x8*>(
        &hbuf[(size_t)NSTEP * BB * HID + base]);
    float4 f0, f1;
    f0.x = bf2f(((unsigned short*)&v)[0]); f0.y = bf2f(((unsigned short*)&v)[1]);
    f0.z = bf2f(((unsigned short*)&v)[2]); f0.w = bf2f(((unsigned short*)&v)[3]);
    f1.x = bf2f(((unsigned short*)&v)[4]); f1.y = bf2f(((unsigned short*)&v)[5]);
    f1.z = bf2f(((unsigned short*)&v)[6]); f1.w = bf2f(((unsigned short*)&v)[7]);
    *reinterpret_cast<float4*>(&out[tail + base])     = f0;
    *reinterpret_cast<float4*>(&out[tail + base + 4]) = f1;
    return;
  }
  i -= HN8;
  if (i < C4) {
    int base = i * 4;
    *reinterpret_cast<float4*>(&out[tail + (size_t)BB * HID + base]) =
        *reinterpret_cast<const float4*>(&c_ws[base]);
  }
}

// ---------------------------------------------------------------------------
extern "C" void kernel_launch(void* const* d_in, const int* in_sizes, int n_in,
                              void* d_out, int out_size, void* d_ws, size_t ws_size,
                              hipStream_t stream)
{
  const int*   tgt  = (const int*)d_in[0];
  const float* h0   = (const float*)d_in[1];
  const float* c0   = (const float*)d_in[2];
  const float* emb  = (const float*)d_in[5];
  const float* w_ih = (const float*)d_in[6];
  const float* w_hh = (const float*)d_in[7];
  const float* b_ih = (const float*)d_in[8];
  const float* b_hh = (const float*)d_in[9];
  float* out = (float*)d_out;

  const size_t FLAGS_BYTES = (size_t)NSTEP * 4 * 64 * 16;          // 16B stride
  const size_t HBUF_BYTES  = (size_t)(NSTEP + 1) * BB * HID * 2;   // bf16 history

  char* p = (char*)d_ws;
  unsigned short* wih_bf = (unsigned short*)p;  p += (size_t)G4 * HID * 2;
  unsigned short* whh_bf = (unsigned short*)p;  p += (size_t)G4 * HID * 2;
  float*          bias   = (float*)p;           p += (size_t)G4 * 4;
  unsigned int*   hb0    = (unsigned int*)p;    p += (size_t)BB * HID * 2;
  unsigned int*   hb1    = (unsigned int*)p;    p += (size_t)BB * HID * 2;
  unsigned int*   hhist  = (unsigned int*)p;    p += HBUF_BYTES;
  float*          c_ws   = (float*)p;           p += (size_t)BB * HID * 4;
  unsigned int*   flags  = (unsigned int*)p;    p += FLAGS_BYTES;

  size_t fixed = (size_t)(p - (char*)d_ws);
  size_t rem = (ws_size > fixed) ? ws_size - fixed : 0;
  int Tc = (int)((rem > 262144 ? rem - 262144 : 0) / 1179648);
  if (Tc > NSTEP) Tc = NSTEP;
  if (Tc < 1) return;

  int MtMax = ((Tc * BB + 127) / 128) * 128;
  unsigned short* A_bf = (unsigned short*)p; p += (size_t)MtMax * HID * 2;
  float*          gin  = (float*)p;

  (void)hipMemsetAsync(flags, 0, FLAGS_BYTES, stream);
  conv_f32_bf16<<<dim3((G4 * HID) / 8 / 256), 256, 0, stream>>>(w_ih, wih_bf, G4 * HID);
  conv_f32_bf16<<<dim3((G4 * HID) / 8 / 256), 256, 0, stream>>>(w_hh, whh_bf, G4 * HID);
  bias_add<<<dim3(G4 / 256), 256, 0, stream>>>(b_ih, b_hh, bias);
  conv_f32_bf16<<<dim3((BB * HID) / 8 / 256), 256, 0, stream>>>(h0, (unsigned short*)hb0, BB * HID);

  for (int t0 = 0; t0 < NSTEP; t0 += Tc) {
    int tc = (NSTEP - t0 < Tc) ? (NSTEP - t0) : Tc;
    int Mt = ((tc * BB + 127) / 128) * 128;
    conv_A<<<dim3(Mt / 2), 256, 0, stream>>>(tgt, emb, A_bf, t0, tc);
    gin_mfma<<<dim3(Mt / 128, G4 / 128), 256, 0, stream>>>(A_bf, wih_bf, bias, gin, tc * BB);

    void* kargs[] = { (void*)&whh_bf, (void*)&gin, (void*)&hb0, (void*)&hb1,
                      (void*)&hhist, (void*)&c_ws, (void*)&c0, (void*)&flags,
                      (void*)&t0, (void*)&tc };
    (void)hipLaunchCooperativeKernel((void*)lstm_persist, dim3(256), dim3(256),
                                     kargs, 0, stream);
  }

  const int TOT = BB * NSTEP * HID / 8 + BB * HID / 8 + BB * HID / 4;
  out_expand<<<dim3((TOT + 255) / 256), 256, 0, stream>>>(
      (const unsigned short*)hhist, c_ws, out);
}